// Round 19
// baseline (188.357 us; speedup 1.0000x reference)
//
#include <hip/hip_runtime.h>

// Problem constants
constexpr int GG    = 512;          // graphs
constexpr int NPG   = 128;          // nodes per graph
constexpr int FIN   = 64;
constexpr int DD    = 128;
constexpr int RR    = 4;
constexpr int NN    = GG * NPG;     // 65536 nodes
constexpr int EE    = 1572864;      // edges
constexpr int SLC   = 4096;         // per-graph record slice (avg 3072, sd ~55)
constexpr int HSTR  = 136;          // hG padded row stride in u16 (68 dwords)

typedef __attribute__((ext_vector_type(8))) short bf16x8;
typedef __attribute__((ext_vector_type(4))) float f32x4;
typedef __attribute__((ext_vector_type(2))) float f32x2;
typedef unsigned short u16;
typedef unsigned int   u32;

__device__ __forceinline__ u32 bf16_rne(float x) {
    u32 u = __float_as_uint(x);
    return (u + 0x7FFFu + ((u >> 16) & 1u)) >> 16;
}

// async global->LDS DMA, 16 B per lane; LDS side must be uniform-base + lane*16
__device__ __forceinline__ void gl_lds16(const void* g, void* l) {
    __builtin_amdgcn_global_load_lds((const __attribute__((address_space(1))) u32*)g,
                                     (__attribute__((address_space(3))) u32*)l, 16, 0, 0);
}

// ---------------- front: binA + prep -----------------------------------------
// blocks [0,384): binA, 4096 edges each (vs r17's 192x8192: 2x parallelism,
// half the serial atomic chain) | [384,424): prep 10 layer mats via LDS tile
// transpose (r17 read W with 512B stride -> uncoalesced; now both read and
// write are coalesced) | [424,426): prep wtE.
// NOTE (r18): hipLaunchCooperativeKernel silently failed in this harness
// (out stayed zero) — two-kernel structure is the supported path.

__global__ __launch_bounds__(256, 2) void k_front(const int* __restrict__ ei,
                                                  const int* __restrict__ ea,
                                                  u32* __restrict__ bcur,
                                                  u16* __restrict__ binned,
                                                  const float* __restrict__ W_root,
                                                  const float* __restrict__ W_rel,
                                                  const float* __restrict__ W_emb,
                                                  u16* __restrict__ wtH) {
    __shared__ u32 sRec[4096];                 // 16 KB staged rec|bucket (binA)
    __shared__ int bh[512];
    __shared__ int lcur[512];
    __shared__ float tile[32 * 129];           // 16.5 KB transpose tile (prep)
    int tid = threadIdx.x;
    int bid = blockIdx.x;

    if (bid < 384) {
        // ---- binA: LDS histogram -> per-(block,bucket) run reservation ----
        // rec = locSrc(7) | loc(7)<<7 | rel(2)<<14 (edges are within-graph)
        int e0 = bid * 4096;                   // 384 blocks cover EE exactly
        bh[tid] = 0; bh[tid + 256] = 0;
        __syncthreads();
        for (int i = 0; i < 16; ++i) {
            int e = e0 + i * 256 + tid;
            int src = ei[e];
            int dst = ei[EE + e];
            int a   = ea[e];
            int g   = dst >> 7;                // graph id = bucket
            u32 rec = (u32)(src & 127) | ((u32)(dst & 127) << 7) | ((u32)a << 14);
            sRec[i * 256 + tid] = rec | ((u32)g << 16);
            atomicAdd(&bh[g], 1);
        }
        __syncthreads();
        lcur[tid]       = tid * SLC +
                          (int)atomicAdd(&bcur[tid], (u32)bh[tid]);
        lcur[tid + 256] = (tid + 256) * SLC +
                          (int)atomicAdd(&bcur[tid + 256], (u32)bh[tid + 256]);
        __syncthreads();
        for (int i = 0; i < 16; ++i) {
            u32 r = sRec[i * 256 + tid];
            int pos = atomicAdd(&lcur[r >> 16], 1);
            binned[pos] = (u16)(r & 0xFFFFu);
        }
    } else if (bid < 424) {
        // ---- prep layer mats: 4 blocks/mat, 32 k-rows x 128 n per block ----
        int pb = bid - 384;                    // 0..39
        int mat = pb >> 2;                     // 0..9
        int k0 = (pb & 3) * 32;
        int l = mat / 5, m5 = mat - l * 5;
        const float* Wsrc = (m5 == 0) ? (W_root + l * 16384)
                                      : (W_rel + (size_t)(l * RR + (m5 - 1)) * 16384);
        for (int i = 0; i < 16; ++i) {         // coalesced read (n fastest)
            int k = k0 + (tid >> 7) + i * 2;
            int n = tid & 127;
            tile[(k - k0) * 129 + n] = Wsrc[k * 128 + n];
        }
        __syncthreads();
        for (int i = 0; i < 16; ++i) {         // coalesced write (k fastest)
            int kk = tid & 31;
            int n  = (tid >> 5) + i * 8;
            wtH[mat * 16384 + n * 128 + k0 + kk] = (u16)bf16_rne(tile[kk * 129 + n]);
        }
    } else {
        // ---- prep wtE = W_emb^T (128 n x 64 k) at +163840, 2 blocks ----
        int k0 = (bid - 424) * 32;
        for (int i = 0; i < 16; ++i) {
            int k = k0 + (tid >> 7) + i * 2;
            int n = tid & 127;
            tile[(k - k0) * 129 + n] = W_emb[k * 128 + n];
        }
        __syncthreads();
        for (int i = 0; i < 16; ++i) {
            int kk = tid & 31;
            int n  = (tid >> 5) + i * 8;
            wtH[163840 + n * 64 + k0 + kk] = (u16)bf16_rne(tile[kk * 129 + n]);
        }
    }
}

// ---------------- fused sort + embed + two-layer RGCN + max-pool -------------
// One block per graph, 512 threads = 8 waves; wave owns a 16-node M-strip.
// Prologue counting-sorts the graph's own rec slice entirely in LDS/registers
// (hist over 512 keys = rel*128+loc, scan, rank) -> sIdx/sOffs/sInv. Gather is
// A-layout-direct in TWO 64-col halves (register-budget safe — r16's single
// pass spilled), accumulating in f32x2 pairs (v_pk_add_f32: 3 VALU/pair vs 4).
// LDS ~69.6 KB -> 2 blocks/CU.

__global__ __launch_bounds__(512, 4) void k_fused(const float* __restrict__ x,
                                                  const float* __restrict__ b_emb,
                                                  float* __restrict__ outF,
                                                  const u16* __restrict__ wtH,
                                                  const float* __restrict__ bias,
                                                  const u16* __restrict__ binned,
                                                  const u32* __restrict__ bcur) {
    __shared__ __align__(16) u16 hG[128 * HSTR];   // 34816 B current-layer h
    __shared__ __align__(16) u16 sQ[2][4096];      // 16384 B B k-quarter dbuf
    __shared__ u16   sIdx[SLC];                    //  8192 B sorted local src
    __shared__ int   sOffs[513];                   //  2052 B segment starts + sentinel
    __shared__ int   sCnt[512];                    //  2048 B hist / rank cursor
    __shared__ float sInv[512];                    //  2048 B inverse counts
    __shared__ float red[8][128];                  //  4096 B pool reduce

    int tid  = threadIdx.x;
    int wave = tid >> 6, lane = tid & 63;
    int mm   = lane & 15;            // MFMA m/n lane == gather node index
    int qd   = lane >> 4;            // MFMA quad == gather col-chunk selector
    int gr   = blockIdx.x;           // graph id
    int row0g = gr * NPG;            // global row base
    int strip = wave * 16;           // local node base of this wave
    const u16* wtE = wtH + 163840;   // embed matrix (128 n x 64 k)

    // stage k-quarter `step` into sQ[bufi]: layer mats, row stride 128
    auto stage = [&](int step, int bufi) {
        const u16* src = wtH + (step >> 2) * 16384 + (step & 3) * 32;
        int u = tid;                 // 512 granules, 1/thread
        int n = u >> 2, j = u & 3;
        gl_lds16(src + n * 128 + ((j ^ ((n >> 1) & 3)) * 8), &sQ[bufi][u * 8]);
    };
    // stage embed k-quarter q (K=64 mat, row stride 64)
    auto stageE = [&](int q, int bufi) {
        const u16* src = wtE + q * 32;
        int u = tid;
        int n = u >> 2, j = u & 3;
        gl_lds16(src + n * 64 + ((j ^ ((n >> 1) & 3)) * 8), &sQ[bufi][u * 8]);
    };

    f32x4 acc[8];
    auto mfma_quarter = [&](int bufi, bf16x8 A) {
        const u16* buf = sQ[bufi];
#pragma unroll
        for (int nt = 0; nt < 8; ++nt) {
            int n = nt * 16 + mm;
            int slot = n * 4 + (qd ^ ((n >> 1) & 3));
            bf16x8 B = *(const bf16x8*)&buf[slot * 8];
            acc[nt] = __builtin_amdgcn_mfma_f32_16x16x32_bf16(A, B, acc[nt], 0, 0, 0);
        }
    };

    // A-layout-direct mean-aggregate, TWO 64-col halves, f32x2 accumulators
    auto gather = [&](int rel, bf16x8* AH) {
        int key = (rel << 7) + strip + mm;
        int r0 = sOffs[key];
        int r1 = sOffs[key + 1];
        float s = sInv[key];
#pragma unroll
        for (int h = 0; h < 2; ++h) {
            int cb = h * 64 + qd * 8;
            f32x2 ax[8];
#pragma unroll
            for (int i = 0; i < 8; ++i) ax[i] = (f32x2){0.f, 0.f};
            auto upk8 = [&](int ks, uint4 u) {
                ax[ks*4+0] += (f32x2){__uint_as_float(u.x << 16),
                                      __uint_as_float(u.x & 0xffff0000u)};
                ax[ks*4+1] += (f32x2){__uint_as_float(u.y << 16),
                                      __uint_as_float(u.y & 0xffff0000u)};
                ax[ks*4+2] += (f32x2){__uint_as_float(u.z << 16),
                                      __uint_as_float(u.z & 0xffff0000u)};
                ax[ks*4+3] += (f32x2){__uint_as_float(u.w << 16),
                                      __uint_as_float(u.w & 0xffff0000u)};
            };
            int j = r0;
            for (; j + 2 <= r1; j += 2) {        // 2 edges -> 4 reads in flight
                int rb0 = (int)sIdx[j]     * HSTR + cb;
                int rb1 = (int)sIdx[j + 1] * HSTR + cb;
                uint4 a0 = *(const uint4*)&hG[rb0];
                uint4 a1 = *(const uint4*)&hG[rb0 + 32];
                uint4 b0 = *(const uint4*)&hG[rb1];
                uint4 b1 = *(const uint4*)&hG[rb1 + 32];
                upk8(0, a0); upk8(1, a1); upk8(0, b0); upk8(1, b1);
            }
            if (j < r1) {
                int rb = (int)sIdx[j] * HSTR + cb;
                uint4 a0 = *(const uint4*)&hG[rb];
                uint4 a1 = *(const uint4*)&hG[rb + 32];
                upk8(0, a0); upk8(1, a1);
            }
#pragma unroll
            for (int k2 = 0; k2 < 2; ++k2) {
                uint4 u;
                u.x = bf16_rne(ax[k2*4+0].x * s) | (bf16_rne(ax[k2*4+0].y * s) << 16);
                u.y = bf16_rne(ax[k2*4+1].x * s) | (bf16_rne(ax[k2*4+1].y * s) << 16);
                u.z = bf16_rne(ax[k2*4+2].x * s) | (bf16_rne(ax[k2*4+2].y * s) << 16);
                u.w = bf16_rne(ax[k2*4+3].x * s) | (bf16_rne(ax[k2*4+3].y * s) << 16);
                AH[h * 2 + k2] = *(bf16x8*)&u;
            }
        }
    };

    // ---- prologue: in-LDS counting sort of this graph's rec slice ----
    stageE(0, 0);                                // embed quarter0 DMA (sQ unused by sort)
    int cnt = (int)bcur[gr];
    if (cnt > SLC) cnt = SLC;                    // never in practice (18 sigma)
    uint4 myRec = *(const uint4*)&binned[gr * SLC + tid * 8];   // 8 recs/thread
    sCnt[tid] = 0;
    __syncthreads();
    int base8 = tid * 8;
#pragma unroll
    for (int i = 0; i < 8; ++i) {
        if (base8 + i < cnt) {
            u32 w = ((const u32*)&myRec)[i >> 1];
            u32 rec = (i & 1) ? (w >> 16) : (w & 0xFFFFu);
            atomicAdd(&sCnt[rec >> 7], 1);
        }
    }
    __syncthreads();
    int c = sCnt[tid];
    sOffs[tid] = c;
    __syncthreads();
    for (int o = 1; o < 512; o <<= 1) {          // inclusive scan over 512 keys
        int t = (tid >= o) ? sOffs[tid - o] : 0;
        __syncthreads();
        sOffs[tid] += t;
        __syncthreads();
    }
    int ex = sOffs[tid] - c;
    sOffs[tid] = ex;
    sCnt[tid]  = ex;                             // rank cursor
    sInv[tid]  = 1.0f / (float)(c > 0 ? c : 1);
    if (tid == 0) sOffs[512] = cnt;
    __syncthreads();
#pragma unroll
    for (int i = 0; i < 8; ++i) {                // rank-scatter local src indices
        if (base8 + i < cnt) {
            u32 w = ((const u32*)&myRec)[i >> 1];
            u32 rec = (i & 1) ? (w >> 16) : (w & 0xFFFFu);
            int pos = atomicAdd(&sCnt[rec >> 7], 1);
            sIdx[pos] = (u16)(rec & 127u);
        }
    }
    __syncthreads();                             // sort done; embed buf0 drained

    // ---- embed: hG = bf16(x @ W_emb + b_emb), A from global x ----
    {
#pragma unroll
        for (int nt = 0; nt < 8; ++nt) {
            float bv = b_emb[nt * 16 + mm];
            acc[nt] = (f32x4){bv, bv, bv, bv};
        }
        bf16x8 AE[2];
#pragma unroll
        for (int ks = 0; ks < 2; ++ks) {         // k = ks*32 + qd*8 + 0..7
            const float* xp = &x[(size_t)(row0g + strip + mm) * FIN + ks * 32 + qd * 8];
            float4 a = *(const float4*)xp;
            float4 b = *(const float4*)(xp + 4);
            uint4 u;
            u.x = bf16_rne(a.x) | (bf16_rne(a.y) << 16);
            u.y = bf16_rne(a.z) | (bf16_rne(a.w) << 16);
            u.z = bf16_rne(b.x) | (bf16_rne(b.y) << 16);
            u.w = bf16_rne(b.z) | (bf16_rne(b.w) << 16);
            AE[ks] = *(bf16x8*)&u;
        }
        stageE(1, 1);
        mfma_quarter(0, AE[0]);
        __syncthreads();                         // buf1 drained; buf0 free
        stage(0, 0);                             // L0 mat0 q0 -> buf0
        mfma_quarter(1, AE[1]);
        __syncthreads();                         // buf0 drained; buf1 free
#pragma unroll
        for (int nt = 0; nt < 8; ++nt)           // write h0 rows into hG (no relu)
#pragma unroll
            for (int r = 0; r < 4; ++r)
                hG[(strip + qd * 4 + r) * HSTR + nt * 16 + mm] =
                    (u16)bf16_rne(acc[nt][r]);
        __syncthreads();                         // hG visible to all waves
    }

    // ---- two layers x 5 matrices ----
    for (int L = 0; L < 2; ++L) {
        const float* bl = bias + L * DD;
#pragma unroll
        for (int i = 0; i < 8; ++i) acc[i] = (f32x4){0.f, 0.f, 0.f, 0.f};

        bf16x8 AH[4];
#pragma unroll
        for (int ks = 0; ks < 4; ++ks)           // root A direct from hG
            AH[ks] = *(const bf16x8*)&hG[(strip + mm) * HSTR + ks * 32 + qd * 8];

        for (int m = 0; m < 5; ++m) {
#pragma unroll
            for (int q = 0; q < 4; ++q) {
                int step = L * 20 + m * 4 + q;
                if (step + 1 < 40) stage(step + 1, (step + 1) & 1);
                mfma_quarter(step & 1, AH[q]);
                __syncthreads();                 // next buf drained; this buf free
            }
            if (m < 4) gather(m, AH);            // next mat's A, in-register
        }

        if (L == 0) {
            // h1 -> hG (all hG readers done: root-A + gathers precede mat4 barriers)
#pragma unroll
            for (int nt = 0; nt < 8; ++nt) {
                float bv = bl[nt * 16 + mm];
#pragma unroll
                for (int r = 0; r < 4; ++r)
                    hG[(strip + qd * 4 + r) * HSTR + nt * 16 + mm] =
                        (u16)bf16_rne(fmaxf(acc[nt][r] + bv, 0.f));
            }
            __syncthreads();                     // h1 visible to all waves
        } else {
            // max-pool: per-wave column max -> LDS -> plain store
#pragma unroll
            for (int nt = 0; nt < 8; ++nt) {
                float bv = bl[nt * 16 + mm];
                float v = fmaxf(fmaxf(acc[nt][0], acc[nt][1]),
                                fmaxf(acc[nt][2], acc[nt][3])) + bv;
                v = fmaxf(v, 0.f);               // relu(max) == max(relu)
                v = fmaxf(v, __shfl_xor(v, 16));
                v = fmaxf(v, __shfl_xor(v, 32));
                if (lane < 16) red[wave][nt * 16 + mm] = v;
            }
            __syncthreads();
            if (tid < 128) {
                float mx = red[0][tid];
#pragma unroll
                for (int w = 1; w < 8; ++w) mx = fmaxf(mx, red[w][tid]);
                outF[gr * DD + tid] = mx;
            }
        }
    }
}

// ---------------- launch ----------------

extern "C" void kernel_launch(void* const* d_in, const int* in_sizes, int n_in,
                              void* d_out, int out_size, void* d_ws, size_t ws_size,
                              hipStream_t stream) {
    const float* x      = (const float*)d_in[0];
    const int*   ei     = (const int*)  d_in[1];
    const int*   ea     = (const int*)  d_in[2];
    const float* W_emb  = (const float*)d_in[3];
    const float* b_emb  = (const float*)d_in[4];
    const float* W_root = (const float*)d_in[5];
    const float* W_rel  = (const float*)d_in[6];
    const float* bias   = (const float*)d_in[7];
    float* out = (float*)d_out;

    char* p = (char*)d_ws;
    u32* bcur   = (u32*)p; p += 2048;                               // 512 cursors (memset 0)
    u16* binned = (u16*)p; p += (size_t)GG * SLC * 2;               // 4.19 MB static slices
    u16* wtH    = (u16*)p; p += (size_t)(10 * 16384 + 8192) * 2;    // 0.35 MB (+wtE)

    hipMemsetAsync(bcur, 0, 2048, stream);

    k_front<<<426, 256, 0, stream>>>(ei, ea, bcur, binned,
                                     W_root, W_rel, W_emb, wtH);
    k_fused<<<GG, 512, 0, stream>>>(x, b_emb, out, wtH, bias, binned, bcur);
}

// Round 21
// 184.340 us; speedup vs baseline: 1.0218x; 1.0218x over previous
//
#include <hip/hip_runtime.h>

// Problem constants
constexpr int GG    = 512;          // graphs
constexpr int NPG   = 128;          // nodes per graph
constexpr int FIN   = 64;
constexpr int DD    = 128;
constexpr int RR    = 4;
constexpr int NN    = GG * NPG;     // 65536 nodes
constexpr int EE    = 1572864;      // edges
constexpr int SLC   = 4096;         // per-graph record slice (avg 3072, sd ~55)
constexpr int HSTR  = 136;          // hG padded row stride in u16 (17 granules: odd -> conflict-free)

typedef __attribute__((ext_vector_type(8))) short bf16x8;
typedef __attribute__((ext_vector_type(4))) float f32x4;
typedef __attribute__((ext_vector_type(2))) float f32x2;
typedef unsigned short u16;
typedef unsigned int   u32;

__device__ __forceinline__ u32 bf16_rne(float x) {
    u32 u = __float_as_uint(x);
    return (u + 0x7FFFu + ((u >> 16) & 1u)) >> 16;
}

// async global->LDS DMA, 16 B per lane; LDS side must be uniform-base + lane*16
__device__ __forceinline__ void gl_lds16(const void* g, void* l) {
    __builtin_amdgcn_global_load_lds((const __attribute__((address_space(1))) u32*)g,
                                     (__attribute__((address_space(3))) u32*)l, 16, 0, 0);
}

// ---------------- front: binA + prep (unchanged from r19 — two null results) --

__global__ __launch_bounds__(256, 2) void k_front(const int* __restrict__ ei,
                                                  const int* __restrict__ ea,
                                                  u32* __restrict__ bcur,
                                                  u16* __restrict__ binned,
                                                  const float* __restrict__ W_root,
                                                  const float* __restrict__ W_rel,
                                                  const float* __restrict__ W_emb,
                                                  u16* __restrict__ wtH) {
    __shared__ u32 sRec[4096];                 // 16 KB staged rec|bucket (binA)
    __shared__ int bh[512];
    __shared__ int lcur[512];
    __shared__ float tile[32 * 129];           // 16.5 KB transpose tile (prep)
    int tid = threadIdx.x;
    int bid = blockIdx.x;

    if (bid < 384) {
        // ---- binA: LDS histogram -> per-(block,bucket) run reservation ----
        // rec = locSrc(7) | loc(7)<<7 | rel(2)<<14 (edges are within-graph)
        int e0 = bid * 4096;                   // 384 blocks cover EE exactly
        bh[tid] = 0; bh[tid + 256] = 0;
        __syncthreads();
        for (int i = 0; i < 16; ++i) {
            int e = e0 + i * 256 + tid;
            int src = ei[e];
            int dst = ei[EE + e];
            int a   = ea[e];
            int g   = dst >> 7;                // graph id = bucket
            u32 rec = (u32)(src & 127) | ((u32)(dst & 127) << 7) | ((u32)a << 14);
            sRec[i * 256 + tid] = rec | ((u32)g << 16);
            atomicAdd(&bh[g], 1);
        }
        __syncthreads();
        lcur[tid]       = tid * SLC +
                          (int)atomicAdd(&bcur[tid], (u32)bh[tid]);
        lcur[tid + 256] = (tid + 256) * SLC +
                          (int)atomicAdd(&bcur[tid + 256], (u32)bh[tid + 256]);
        __syncthreads();
        for (int i = 0; i < 16; ++i) {
            u32 r = sRec[i * 256 + tid];
            int pos = atomicAdd(&lcur[r >> 16], 1);
            binned[pos] = (u16)(r & 0xFFFFu);
        }
    } else if (bid < 424) {
        // ---- prep layer mats: 4 blocks/mat, 32 k-rows x 128 n per block ----
        int pb = bid - 384;                    // 0..39
        int mat = pb >> 2;                     // 0..9
        int k0 = (pb & 3) * 32;
        int l = mat / 5, m5 = mat - l * 5;
        const float* Wsrc = (m5 == 0) ? (W_root + l * 16384)
                                      : (W_rel + (size_t)(l * RR + (m5 - 1)) * 16384);
        for (int i = 0; i < 16; ++i) {         // coalesced read (n fastest)
            int k = k0 + (tid >> 7) + i * 2;
            int n = tid & 127;
            tile[(k - k0) * 129 + n] = Wsrc[k * 128 + n];
        }
        __syncthreads();
        for (int i = 0; i < 16; ++i) {         // coalesced write (k fastest)
            int kk = tid & 31;
            int n  = (tid >> 5) + i * 8;
            wtH[mat * 16384 + n * 128 + k0 + kk] = (u16)bf16_rne(tile[kk * 129 + n]);
        }
    } else {
        // ---- prep wtE = W_emb^T (128 n x 64 k) at +163840, 2 blocks ----
        int k0 = (bid - 424) * 32;
        for (int i = 0; i < 16; ++i) {
            int k = k0 + (tid >> 7) + i * 2;
            int n = tid & 127;
            tile[(k - k0) * 129 + n] = W_emb[k * 128 + n];
        }
        __syncthreads();
        for (int i = 0; i < 16; ++i) {
            int kk = tid & 31;
            int n  = (tid >> 5) + i * 8;
            wtH[163840 + n * 64 + k0 + kk] = (u16)bf16_rne(tile[kk * 129 + n]);
        }
    }
}

// ---------------- fused sort + embed + two-layer RGCN + max-pool -------------
// One block per graph, 512 threads = 8 waves; wave owns a 16-node M-strip.
// r20 changes (barrier/LDS-pipe attack): B staged in HALF-mats (16 KB dbuf
// chunks) -> 20 steps instead of 40 (barriers 45 -> ~27, 16 MFMA + 16 b128
// per inter-barrier span); sort prefix via intra-wave __shfl_up scan (2
// barriers vs 18); segment end = post-scatter sCnt[key] (no sentinel); red
// overlays dead sIdx. LDS = exactly 81920 B -> 2 blocks/CU (2 x 80 KB).

__global__ __launch_bounds__(512, 4) void k_fused(const float* __restrict__ x,
                                                  const float* __restrict__ b_emb,
                                                  float* __restrict__ outF,
                                                  const u16* __restrict__ wtH,
                                                  const float* __restrict__ bias,
                                                  const u16* __restrict__ binned,
                                                  const u32* __restrict__ bcur) {
    __shared__ __align__(16) u16 hG[128 * HSTR];   // 34816 B current-layer h
    __shared__ __align__(16) u16 sQ[2][8192];      // 32768 B B half-mat dbuf
    __shared__ __align__(16) u16 sIdx[SLC];        //  8192 B sorted src (alias: wtot, red)
    __shared__ int   sOffs[512];                   //  2048 B segment starts
    __shared__ int   sCnt[512];                    //  2048 B hist / cursor / seg ENDS
    __shared__ float sInv[512];                    //  2048 B inverse counts
                                                   //  total 81920 B exactly

    int tid  = threadIdx.x;
    int wave = tid >> 6, lane = tid & 63;
    int mm   = lane & 15;            // MFMA m/n lane == gather node index
    int qd   = lane >> 4;            // MFMA quad == gather col-chunk selector
    int gr   = blockIdx.x;           // graph id
    int row0g = gr * NPG;            // global row base
    int strip = wave * 16;           // local node base of this wave
    const u16* wtE = wtH + 163840;   // embed matrix (128 n x 64 k)

    // stage half-mat `step` (mat step>>1, k-half step&1) into sQ[bufi].
    // 1024 granules; slot(n, j) = n*8 + (j ^ (n&7)), j = ks*4 + quad.
    auto stage = [&](int step, int bufi) {
        const u16* src = wtH + (step >> 1) * 16384 + (step & 1) * 64;
#pragma unroll
        for (int i = 0; i < 2; ++i) {
            int u = i * 512 + tid;
            int n = u >> 3, j = u & 7;
            gl_lds16(src + n * 128 + ((j ^ (n & 7)) * 8), &sQ[bufi][u * 8]);
        }
    };
    // stage embed matrix (K=64 -> exactly one 16 KB half-buffer)
    auto stageE = [&](int bufi) {
#pragma unroll
        for (int i = 0; i < 2; ++i) {
            int u = i * 512 + tid;
            int n = u >> 3, j = u & 7;
            gl_lds16(wtE + n * 64 + ((j ^ (n & 7)) * 8), &sQ[bufi][u * 8]);
        }
    };

    f32x4 acc[8];
    // one k-half: 16 B-frag reads + 16 MFMAs. slot(n, j) with j = ks*4 + qd
    auto mfma_half = [&](int bufi, bf16x8 A0, bf16x8 A1) {
        const u16* buf = sQ[bufi];
#pragma unroll
        for (int nt = 0; nt < 8; ++nt) {
            int n = nt * 16 + mm;
            int g0 = n * 8 + ((0 * 4 + qd) ^ (n & 7));
            int g1 = n * 8 + ((1 * 4 + qd) ^ (n & 7));
            bf16x8 B0 = *(const bf16x8*)&buf[g0 * 8];
            bf16x8 B1 = *(const bf16x8*)&buf[g1 * 8];
            f32x4 a = acc[nt];
            a = __builtin_amdgcn_mfma_f32_16x16x32_bf16(A0, B0, a, 0, 0, 0);
            a = __builtin_amdgcn_mfma_f32_16x16x32_bf16(A1, B1, a, 0, 0, 0);
            acc[nt] = a;
        }
    };

    // A-layout-direct mean-aggregate, TWO 64-col halves, f32x2 accumulators
    auto gather = [&](int rel, bf16x8* AH) {
        int key = (rel << 7) + strip + mm;
        int r0 = sOffs[key];
        int r1 = sCnt[key];                      // post-scatter cursor == segment end
        float s = sInv[key];
#pragma unroll
        for (int h = 0; h < 2; ++h) {
            int cb = h * 64 + qd * 8;
            f32x2 ax[8];
#pragma unroll
            for (int i = 0; i < 8; ++i) ax[i] = (f32x2){0.f, 0.f};
            auto upk8 = [&](int ks, uint4 u) {
                ax[ks*4+0] += (f32x2){__uint_as_float(u.x << 16),
                                      __uint_as_float(u.x & 0xffff0000u)};
                ax[ks*4+1] += (f32x2){__uint_as_float(u.y << 16),
                                      __uint_as_float(u.y & 0xffff0000u)};
                ax[ks*4+2] += (f32x2){__uint_as_float(u.z << 16),
                                      __uint_as_float(u.z & 0xffff0000u)};
                ax[ks*4+3] += (f32x2){__uint_as_float(u.w << 16),
                                      __uint_as_float(u.w & 0xffff0000u)};
            };
            int j = r0;
            for (; j + 2 <= r1; j += 2) {        // 2 edges -> 4 reads in flight
                int rb0 = (int)sIdx[j]     * HSTR + cb;
                int rb1 = (int)sIdx[j + 1] * HSTR + cb;
                uint4 a0 = *(const uint4*)&hG[rb0];
                uint4 a1 = *(const uint4*)&hG[rb0 + 32];
                uint4 b0 = *(const uint4*)&hG[rb1];
                uint4 b1 = *(const uint4*)&hG[rb1 + 32];
                upk8(0, a0); upk8(1, a1); upk8(0, b0); upk8(1, b1);
            }
            if (j < r1) {
                int rb = (int)sIdx[j] * HSTR + cb;
                uint4 a0 = *(const uint4*)&hG[rb];
                uint4 a1 = *(const uint4*)&hG[rb + 32];
                upk8(0, a0); upk8(1, a1);
            }
#pragma unroll
            for (int k2 = 0; k2 < 2; ++k2) {
                uint4 u;
                u.x = bf16_rne(ax[k2*4+0].x * s) | (bf16_rne(ax[k2*4+0].y * s) << 16);
                u.y = bf16_rne(ax[k2*4+1].x * s) | (bf16_rne(ax[k2*4+1].y * s) << 16);
                u.z = bf16_rne(ax[k2*4+2].x * s) | (bf16_rne(ax[k2*4+2].y * s) << 16);
                u.w = bf16_rne(ax[k2*4+3].x * s) | (bf16_rne(ax[k2*4+3].y * s) << 16);
                AH[h * 2 + k2] = *(bf16x8*)&u;
            }
        }
    };

    // ---- prologue: in-LDS counting sort (shuffle-scan prefix) ----
    stageE(0);                                   // embed DMA into buf0
    int cnt = (int)bcur[gr];
    if (cnt > SLC) cnt = SLC;                    // never in practice (18 sigma)
    uint4 myRec = *(const uint4*)&binned[gr * SLC + tid * 8];   // 8 recs/thread
    sCnt[tid] = 0;
    __syncthreads();
    int base8 = tid * 8;
#pragma unroll
    for (int i = 0; i < 8; ++i) {
        if (base8 + i < cnt) {
            u32 w = ((const u32*)&myRec)[i >> 1];
            u32 rec = (i & 1) ? (w >> 16) : (w & 0xFFFFu);
            atomicAdd(&sCnt[rec >> 7], 1);
        }
    }
    __syncthreads();
    int c = sCnt[tid];
    int v = c;                                   // intra-wave inclusive scan
#pragma unroll
    for (int o = 1; o < 64; o <<= 1) {
        int t = __shfl_up(v, o);
        if (lane >= o) v += t;
    }
    int* wtot = (int*)sIdx;                      // sort-phase scratch (sIdx dead)
    if (lane == 63) wtot[wave] = v;
    __syncthreads();
    int base = 0;
#pragma unroll
    for (int w = 0; w < 8; ++w) {
        int tw = wtot[w];
        if (w < wave) base += tw;
    }
    int ex = base + v - c;
    sOffs[tid] = ex;
    sCnt[tid]  = ex;                             // rank cursor -> becomes seg END
    sInv[tid]  = 1.0f / (float)(c > 0 ? c : 1);
    __syncthreads();
#pragma unroll
    for (int i = 0; i < 8; ++i) {                // rank-scatter local src indices
        if (base8 + i < cnt) {
            u32 w = ((const u32*)&myRec)[i >> 1];
            u32 rec = (i & 1) ? (w >> 16) : (w & 0xFFFFu);
            int pos = atomicAdd(&sCnt[rec >> 7], 1);
            sIdx[pos] = (u16)(rec & 127u);
        }
    }
    __syncthreads();                             // sort done; embed buf0 drained

    // ---- embed: hG = bf16(x @ W_emb + b_emb), A from global x ----
    {
#pragma unroll
        for (int nt = 0; nt < 8; ++nt) {
            float bv = b_emb[nt * 16 + mm];
            acc[nt] = (f32x4){bv, bv, bv, bv};
        }
        bf16x8 AE[2];
#pragma unroll
        for (int ks = 0; ks < 2; ++ks) {         // k = ks*32 + qd*8 + 0..7
            const float* xp = &x[(size_t)(row0g + strip + mm) * FIN + ks * 32 + qd * 8];
            float4 a = *(const float4*)xp;
            float4 b = *(const float4*)(xp + 4);
            uint4 u;
            u.x = bf16_rne(a.x) | (bf16_rne(a.y) << 16);
            u.y = bf16_rne(a.z) | (bf16_rne(a.w) << 16);
            u.z = bf16_rne(b.x) | (bf16_rne(b.y) << 16);
            u.w = bf16_rne(b.z) | (bf16_rne(b.w) << 16);
            AE[ks] = *(bf16x8*)&u;
        }
        stage(0, 1);                             // L0 mat0 half0 -> buf1
        mfma_half(0, AE[0], AE[1]);
#pragma unroll
        for (int nt = 0; nt < 8; ++nt)           // write h0 rows into hG (no relu)
#pragma unroll
            for (int r = 0; r < 4; ++r)
                hG[(strip + qd * 4 + r) * HSTR + nt * 16 + mm] =
                    (u16)bf16_rne(acc[nt][r]);
        __syncthreads();                         // hG visible; buf1 DMA drained
    }

    // ---- two layers x 5 matrices, 2 half-steps each ----
    for (int L = 0; L < 2; ++L) {
        const float* bl = bias + L * DD;
#pragma unroll
        for (int i = 0; i < 8; ++i) acc[i] = (f32x4){0.f, 0.f, 0.f, 0.f};

        bf16x8 AH[4];
#pragma unroll
        for (int ks = 0; ks < 4; ++ks)           // root A direct from hG
            AH[ks] = *(const bf16x8*)&hG[(strip + mm) * HSTR + ks * 32 + qd * 8];

        for (int m = 0; m < 5; ++m) {
#pragma unroll
            for (int h = 0; h < 2; ++h) {
                int s = L * 10 + m * 2 + h;
                if (s + 1 < 20) stage(s + 1, s & 1);
                mfma_half((s + 1) & 1, AH[h * 2], AH[h * 2 + 1]);
                __syncthreads();                 // next buf drained; this buf free
            }
            if (m < 4) gather(m, AH);            // next mat's A, in-register
        }

        if (L == 0) {
            // h1 -> hG (all hG readers done: root-A + gathers precede mat4 barriers)
#pragma unroll
            for (int nt = 0; nt < 8; ++nt) {
                float bv = bl[nt * 16 + mm];
#pragma unroll
                for (int r = 0; r < 4; ++r)
                    hG[(strip + qd * 4 + r) * HSTR + nt * 16 + mm] =
                        (u16)bf16_rne(fmaxf(acc[nt][r] + bv, 0.f));
            }
            __syncthreads();                     // h1 visible to all waves
        } else {
            // max-pool: per-wave column max -> LDS (red overlays dead sIdx) -> store
            float* red = (float*)sIdx;
#pragma unroll
            for (int nt = 0; nt < 8; ++nt) {
                float bv = bl[nt * 16 + mm];
                float vv = fmaxf(fmaxf(acc[nt][0], acc[nt][1]),
                                 fmaxf(acc[nt][2], acc[nt][3])) + bv;
                vv = fmaxf(vv, 0.f);             // relu(max) == max(relu)
                vv = fmaxf(vv, __shfl_xor(vv, 16));
                vv = fmaxf(vv, __shfl_xor(vv, 32));
                if (lane < 16) red[wave * 128 + nt * 16 + mm] = vv;
            }
            __syncthreads();
            if (tid < 128) {
                float mx = red[tid];
#pragma unroll
                for (int w = 1; w < 8; ++w) mx = fmaxf(mx, red[w * 128 + tid]);
                outF[gr * DD + tid] = mx;
            }
        }
    }
}

// ---------------- launch ----------------

extern "C" void kernel_launch(void* const* d_in, const int* in_sizes, int n_in,
                              void* d_out, int out_size, void* d_ws, size_t ws_size,
                              hipStream_t stream) {
    const float* x      = (const float*)d_in[0];
    const int*   ei     = (const int*)  d_in[1];
    const int*   ea     = (const int*)  d_in[2];
    const float* W_emb  = (const float*)d_in[3];
    const float* b_emb  = (const float*)d_in[4];
    const float* W_root = (const float*)d_in[5];
    const float* W_rel  = (const float*)d_in[6];
    const float* bias   = (const float*)d_in[7];
    float* out = (float*)d_out;

    char* p = (char*)d_ws;
    u32* bcur   = (u32*)p; p += 2048;                               // 512 cursors (memset 0)
    u16* binned = (u16*)p; p += (size_t)GG * SLC * 2;               // 4.19 MB static slices
    u16* wtH    = (u16*)p; p += (size_t)(10 * 16384 + 8192) * 2;    // 0.35 MB (+wtE)

    (void)hipMemsetAsync(bcur, 0, 2048, stream);

    k_front<<<426, 256, 0, stream>>>(ei, ea, bcur, binned,
                                     W_root, W_rel, W_emb, wtH);
    k_fused<<<GG, 512, 0, stream>>>(x, b_emb, out, wtH, bias, binned, bcur);
}